// Round 14
// baseline (584.632 us; speedup 1.0000x reference)
//
#include <hip/hip_runtime.h>
#include <math.h>

typedef unsigned short u16;
typedef __attribute__((ext_vector_type(8))) short short8;
typedef __attribute__((ext_vector_type(4))) float f32x4;

#define B_ 4
#define N_ 4096
#define C_ 512
#define H_ 8
#define D_ 64
#define KD_ 256
#define FF_ 2048
#define L_ 2

__device__ __forceinline__ float bf2f(u16 x) {
  return __builtin_bit_cast(float, (unsigned int)x << 16);
}
__device__ __forceinline__ u16 f2bf(float f) {
  unsigned int t = __builtin_bit_cast(unsigned int, f);
  return (u16)((t + 0x7fffu + ((t >> 16) & 1u)) >> 16);
}
// sigmoid-form tanh-GELU: 0.5(1+tanh(u)) == sigmoid(2u); ~8 VALU, no divide
__device__ __forceinline__ float fast_gelu(float t) {
  float z = t * (1.5957691216f + 0.0713548163f * t * t);
  float e = __expf(-z);
  return t * __builtin_amdgcn_rcpf(1.f + e);
}

#define GLD(g, l)                                                             \
  __builtin_amdgcn_global_load_lds(                                           \
      (const __attribute__((address_space(1))) void*)(g),                     \
      (__attribute__((address_space(3))) void*)(l), 16, 0, 0)

#define MFMA16 __builtin_amdgcn_mfma_f32_16x16x32_bf16

// ---------------- f32 -> bf16 convert (single tensor) ----------------
__global__ __launch_bounds__(256) void cvt_kernel(const float* __restrict__ in,
                                                  u16* __restrict__ out, int n4) {
  int i = blockIdx.x * 256 + threadIdx.x;
  if (i >= n4) return;
  float4 v = reinterpret_cast<const float4*>(in)[i];
  ushort4 o;
  o.x = f2bf(v.x); o.y = f2bf(v.y); o.z = f2bf(v.z); o.w = f2bf(v.w);
  reinterpret_cast<ushort4*>(out)[i] = o;
}

// ---------------- fused multi-tensor f32 -> bf16 ----------------
struct Segs {
  const float* src[7];
  u16* dst[7];
  int endblk[7];
};
__global__ __launch_bounds__(256) void cvt_multi_kernel(Segs sg) {
  int b = blockIdx.x;
  int i = 0;
#pragma unroll
  for (int k = 0; k < 6; ++k) i += (b >= sg.endblk[k]);
  int start = (i == 0) ? 0 : sg.endblk[i - 1];
  int idx = (b - start) * 256 + threadIdx.x;
  float4 v = reinterpret_cast<const float4*>(sg.src[i])[idx];
  ushort4 o;
  o.x = f2bf(v.x); o.y = f2bf(v.y); o.z = f2bf(v.z); o.w = f2bf(v.w);
  reinterpret_cast<ushort4*>(sg.dst[i])[idx] = o;
}

// ---------------- bf16 transpose [B,N,C] -> [B,C,N], 64x64 tiles ----------------
__global__ __launch_bounds__(256) void transpose_kernel(const u16* __restrict__ in,
                                                        u16* __restrict__ out) {
  __shared__ u16 T[64][72];
  int n0 = blockIdx.x * 64, c0 = blockIdx.y * 64, b = blockIdx.z;
  const u16* src = in + (long)b * N_ * C_;
  u16* dst = out + (long)b * C_ * N_;
  int t = threadIdx.x;
  int r = t >> 3, cq = (t & 7) * 8;
#pragma unroll
  for (int h = 0; h < 2; ++h) {
    const u16* p = src + (long)(n0 + r + h * 32) * C_ + c0 + cq;
    ushort4 v0 = *reinterpret_cast<const ushort4*>(p);
    ushort4 v1 = *reinterpret_cast<const ushort4*>(p + 4);
    T[r + h * 32][cq + 0] = v0.x; T[r + h * 32][cq + 1] = v0.y;
    T[r + h * 32][cq + 2] = v0.z; T[r + h * 32][cq + 3] = v0.w;
    T[r + h * 32][cq + 4] = v1.x; T[r + h * 32][cq + 5] = v1.y;
    T[r + h * 32][cq + 6] = v1.z; T[r + h * 32][cq + 7] = v1.w;
  }
  __syncthreads();
  int cc = t >> 3, nq = (t & 7) * 8;
#pragma unroll
  for (int h = 0; h < 2; ++h) {
    int cl = cc + h * 32;
    ushort4 w0, w1;
    w0.x = T[nq + 0][cl]; w0.y = T[nq + 1][cl];
    w0.z = T[nq + 2][cl]; w0.w = T[nq + 3][cl];
    w1.x = T[nq + 4][cl]; w1.y = T[nq + 5][cl];
    w1.z = T[nq + 6][cl]; w1.w = T[nq + 7][cl];
    u16* q = dst + (long)(c0 + cl) * N_ + n0 + nq;
    *reinterpret_cast<ushort4*>(q) = w0;
    *reinterpret_cast<ushort4*>(q + 4) = w1;
  }
}

// ---------------- counted-vmcnt single-barrier MFMA GEMM (NT) ----------------
// C[m,j] = sum_k A[m,k]*B[j,k]. BK=32, 4 LDS buffers (3-deep prefetch), ONE
// barrier per K-tile. Counted vmcnt never drains to 0 in the loop.
// NW waves (NW*64 threads); 128^2/4-wave config = 64KB LDS -> 2 blocks/CU so
// co-resident blocks absorb each other's vmcnt/barrier stalls.
// MFMA operands swapped (bf first): lane holds 4 consecutive j for row lane&15.
// Epilogue stages C tile through LDS scratch (wave-private, in As[0..1]).
// EPI: 0 bf16 | 1 bf16 +bias[j] | 2 bf16 gelu(v+bias[j])
template <int BM, int BN, int WM, int WN, int NW, int EPI>
__global__ __launch_bounds__(NW * 64, 2) void gemm8p(
    const u16* __restrict__ A, const u16* __restrict__ B, u16* __restrict__ C,
    const float* __restrict__ bias, int K, int lda, int ldb, int ldc,
    long sAz, long sBz, long sCz) {
  constexpr int BK = 32;
  constexpr int NTHR = NW * 64;
  constexpr int GA = BM * 4 / NTHR, GB = BN * 4 / NTHR, G = GA + GB;
  constexpr int FM = WM / 16, FN = WN / 16;
  constexpr int NWN = BN / WN;
  static_assert(NW * WM * WN == BM * BN, "wave tile coverage mismatch");
  static_assert((NW / NWN) * WM == BM, "M-wave coverage mismatch");
  static_assert(WN == 64, "epilogue assumes WN==64");
  constexpr int ASZ = BM * BK, BSZ = BN * BK;
  constexpr int EPAD = 72;  // scratch row stride (u16)
  static_assert(NW * 16 * EPAD * 2 <= 2 * ASZ * 2, "epilogue scratch overflow");

  __shared__ __attribute__((aligned(16))) u16 As[4][ASZ];
  __shared__ __attribute__((aligned(16))) u16 Bs[4][BSZ];

  A += (long)blockIdx.z * sAz;
  B += (long)blockIdx.z * sBz;
  C += (long)blockIdx.z * sCz;

  int gy = gridDim.y;
  int nwg = gridDim.x * gy;
  int id = blockIdx.x * gy + blockIdx.y;
  int nid = (id & 7) * (nwg >> 3) + (id >> 3);
  int row0 = (nid / gy) * BM, col0 = (nid % gy) * BN;

  int tid = threadIdx.x;
  int lane = tid & 63, wid = tid >> 6;
  int wr = wid / NWN, wc = wid % NWN;
  int lr = lane & 15, q = lane >> 4;

  // hoisted per-thread global stage sources (stage addr = gX[g] + k0)
  const u16* gA[GA];
  const u16* gB[GB];
#pragma unroll
  for (int g = 0; g < GA; ++g) {
    int c = g * NTHR + tid, r = c >> 2, ck = c & 3;
    gA[g] = A + (long)(row0 + r) * lda + ((ck ^ ((r >> 1) & 3)) << 3);
  }
#pragma unroll
  for (int g = 0; g < GB; ++g) {
    int c = g * NTHR + tid, r = c >> 2, ck = c & 3;
    gB[g] = B + (long)(col0 + r) * ldb + ((ck ^ ((r >> 1) & 3)) << 3);
  }

  auto stA = [&](int buf, int k0) {
#pragma unroll
    for (int g = 0; g < GA; ++g)
      GLD(gA[g] + k0, &As[buf][(g * NTHR + tid) * 8]);
  };
  auto stB = [&](int buf, int k0) {
#pragma unroll
    for (int g = 0; g < GB; ++g)
      GLD(gB[g] + k0, &Bs[buf][(g * NTHR + tid) * 8]);
  };
  auto rdA = [&](int buf, int r) {
    return *reinterpret_cast<const short8*>(
        &As[buf][r * 32 + ((q ^ ((r >> 1) & 3)) << 3)]);
  };
  auto rdB = [&](int buf, int r) {
    return *reinterpret_cast<const short8*>(
        &Bs[buf][r * 32 + ((q ^ ((r >> 1) & 3)) << 3)]);
  };

  f32x4 acc[FM][FN] = {};
  int NT = K / BK;  // always a multiple of 4

  stA(0, 0); stB(0, 0);
  stA(1, BK); stB(1, BK);
  stA(2, 2 * BK); stB(2, 2 * BK);

  for (int tt = 0; tt < NT; tt += 4) {
#pragma unroll
    for (int u = 0; u < 4; ++u) {  // buffer index = u (compile-time)
      int t = tt + u;
      bool pf = (t + 3) < NT;
      int kn = (t + 3) * BK;

      // tile t landed; tiles t+1,t+2 (2G loads) stay in flight
      if constexpr (G == 4) asm volatile("s_waitcnt vmcnt(8)" ::: "memory");
      else                  asm volatile("s_waitcnt vmcnt(6)" ::: "memory");
      __builtin_amdgcn_s_barrier();

      short8 bf[FN], af[FM];
#pragma unroll
      for (int nj = 0; nj < FN; ++nj) bf[nj] = rdB(u, wc * WN + nj * 16 + lr);
#pragma unroll
      for (int mi = 0; mi < FM; ++mi) af[mi] = rdA(u, wr * WM + mi * 16 + lr);
      if (pf) { stA((u + 3) & 3, kn); stB((u + 3) & 3, kn); }
      asm volatile("s_waitcnt lgkmcnt(0)" ::: "memory");
      __builtin_amdgcn_sched_barrier(0);
      __builtin_amdgcn_s_setprio(1);
#pragma unroll
      for (int mi = 0; mi < FM; ++mi)
#pragma unroll
        for (int nj = 0; nj < FN; ++nj)
          acc[mi][nj] = MFMA16(bf[nj], af[mi], acc[mi][nj], 0, 0, 0);
      __builtin_amdgcn_s_setprio(0);
    }
  }

  // ---- epilogue: LDS-staged coalesced stores ----
  u16* esc = &As[0][0] + wid * (16 * EPAD);
  int lm = lane & 15, jb4 = (lane >> 4) * 4;
  int erow = lane >> 3, ecol = (lane & 7) * 8;
  float4 bv[FN];
  if constexpr (EPI == 1 || EPI == 2) {
#pragma unroll
    for (int nj = 0; nj < FN; ++nj)
      bv[nj] = *reinterpret_cast<const float4*>(&bias[col0 + wc * WN + nj * 16 + jb4]);
  }
#pragma unroll
  for (int mi = 0; mi < FM; ++mi) {
    long mbase = row0 + wr * WM + mi * 16;
#pragma unroll
    for (int nj = 0; nj < FN; ++nj) {
      f32x4 v = acc[mi][nj];
      ushort4 o;
      if constexpr (EPI == 0) {
        o.x = f2bf(v[0]); o.y = f2bf(v[1]); o.z = f2bf(v[2]); o.w = f2bf(v[3]);
      } else if constexpr (EPI == 1) {
        o.x = f2bf(v[0] + bv[nj].x); o.y = f2bf(v[1] + bv[nj].y);
        o.z = f2bf(v[2] + bv[nj].z); o.w = f2bf(v[3] + bv[nj].w);
      } else {
        o.x = f2bf(fast_gelu(v[0] + bv[nj].x)); o.y = f2bf(fast_gelu(v[1] + bv[nj].y));
        o.z = f2bf(fast_gelu(v[2] + bv[nj].z)); o.w = f2bf(fast_gelu(v[3] + bv[nj].w));
      }
      *reinterpret_cast<ushort4*>(&esc[lm * EPAD + nj * 16 + jb4]) = o;
    }
    asm volatile("s_waitcnt lgkmcnt(0)" ::: "memory");
#pragma unroll
    for (int p = 0; p < 2; ++p) {
      int r = p * 8 + erow;
      uint4 w = *reinterpret_cast<const uint4*>(&esc[r * EPAD + ecol]);
      *reinterpret_cast<uint4*>(&C[(mbase + r) * ldc + col0 + wc * WN + ecol]) = w;
    }
    asm volatile("s_waitcnt lgkmcnt(0)" ::: "memory");
  }
}

// ---------------- generic 128-tile NT MFMA GEMM (phase A) ----------------
// EPI: 7 f32 split-K partial | 10 fused Kp/Vp (z<4: Kp; z>=4: Vp via B2/Cout2)
template <int BM, int BN, int EPI, int SPLITK>
__global__ __launch_bounds__(256, 2) void gemm_nt(
    const u16* __restrict__ A, const u16* B, void* __restrict__ Cout,
    const float* __restrict__ bias, int K, int lda, int ldb, int ldc,
    long sA1, long sB1, long sC1, long sCh, int nz, float alpha,
    const u16* __restrict__ B2, void* __restrict__ Cout2) {
  constexpr int BK = 64;
  constexpr int WM = BM / 2, WN = BN / 2;
  constexpr int FM = WM / 16, FN = WN / 16;
  constexpr int CA = BM / 32, CB = BN / 32;

  __shared__ __attribute__((aligned(16))) u16 As[BM * BK];
  __shared__ __attribute__((aligned(16))) u16 Bs[BN * BK];

  int z, chunk, kv = 0;
  long coff;
  if constexpr (EPI == 10) {
    z = blockIdx.z; chunk = 0;
    kv = z >> 2;
    int zbq = z & 3;
    A += (long)zbq * 131072;
    if (kv) B = B2;
    coff = (long)zbq * 131072;
  } else {
    if constexpr (SPLITK > 1) { z = blockIdx.z % nz; chunk = blockIdx.z / nz; }
    else { z = blockIdx.z; chunk = 0; }
    A += (long)z * sA1;
    B += (long)z * sB1;
    coff = (long)z * sC1 + (long)chunk * sCh;
  }

  int tid = threadIdx.x;
  int lane = tid & 63, wid = tid >> 6;
  int wr = wid >> 1, wc = wid & 1;
  int row0 = blockIdx.x * BM, col0 = blockIdx.y * BN;

  int Kc = K / SPLITK;
  int kbeg = chunk * Kc;

  f32x4 acc[FM][FN] = {};

  for (int k0 = kbeg; k0 < kbeg + Kc; k0 += BK) {
#pragma unroll
    for (int i = 0; i < CA; ++i) {
      int c = tid + i * 256;
      GLD(A + (long)(row0 + (c >> 3)) * lda + k0 + (c & 7) * 8, As + c * 8);
    }
#pragma unroll
    for (int i = 0; i < CB; ++i) {
      int c = tid + i * 256;
      GLD(B + (long)(col0 + (c >> 3)) * ldb + k0 + (c & 7) * 8, Bs + c * 8);
    }
    __syncthreads();

    int lr = lane & 15, lk = (lane >> 4) * 8;
#pragma unroll
    for (int kk = 0; kk < BK; kk += 32) {
      short8 af[FM], bfr[FN];
#pragma unroll
      for (int mi = 0; mi < FM; ++mi)
        af[mi] = *reinterpret_cast<const short8*>(&As[(wr * WM + mi * 16 + lr) * BK + kk + lk]);
#pragma unroll
      for (int nj = 0; nj < FN; ++nj)
        bfr[nj] = *reinterpret_cast<const short8*>(&Bs[(wc * WN + nj * 16 + lr) * BK + kk + lk]);
#pragma unroll
      for (int mi = 0; mi < FM; ++mi)
#pragma unroll
        for (int nj = 0; nj < FN; ++nj)
          acc[mi][nj] = MFMA16(af[mi], bfr[nj], acc[mi][nj], 0, 0, 0);
    }
    __syncthreads();
  }

  int lc = lane & 15, rb = (lane >> 4) * 4;
#pragma unroll
  for (int mi = 0; mi < FM; ++mi) {
#pragma unroll
    for (int nj = 0; nj < FN; ++nj) {
      int j = col0 + wc * WN + nj * 16 + lc;
      int m0 = row0 + wr * WM + mi * 16 + rb;
#pragma unroll
      for (int r = 0; r < 4; ++r) {
        int m = m0 + r;
        float v = acc[mi][nj][r];
        if constexpr (EPI == 10) {
          if (kv == 0)
            reinterpret_cast<u16*>(Cout)[coff + (long)m * 512 + j] = f2bf(v + bias[m]);
          else
            reinterpret_cast<u16*>(Cout2)[coff + (long)j * 256 + m] = f2bf(v + bias[m]);
        } else {  // 7: f32 split-K partial
          reinterpret_cast<float*>(Cout)[coff + (long)m * ldc + j] = v;
        }
      }
    }
  }
}

// ---------------- split-K reduce: sum 8 f32 chunks -> bf16 ----------------
__global__ __launch_bounds__(256) void reduce8_kernel(const float* __restrict__ part,
                                                      u16* __restrict__ out) {
  int i = blockIdx.x * 256 + threadIdx.x;
  const float4* p = reinterpret_cast<const float4*>(part);
  float4 s = p[i];
#pragma unroll
  for (int c = 1; c < 8; ++c) {
    float4 t = p[i + c * 131072];
    s.x += t.x; s.y += t.y; s.z += t.z; s.w += t.w;
  }
  ushort4 o;
  o.x = f2bf(s.x); o.y = f2bf(s.y); o.z = f2bf(s.z); o.w = f2bf(s.w);
  reinterpret_cast<ushort4*>(out)[i] = o;
}

// ---------------- fused attention: S=Q.Kp^T, softmax, O=P.Vp ----------------
__global__ __launch_bounds__(512, 2) void attn_kernel(
    const u16* __restrict__ Q, const u16* __restrict__ Kp,
    const u16* __restrict__ Vpt, u16* __restrict__ O) {
  constexpr int LQ = 72, LKP = 72, LVP = 264, LP = 264;
  __shared__ __attribute__((aligned(16))) u16 Q_s[128 * LQ];
  __shared__ __attribute__((aligned(16))) u16 Kp_s[256 * LKP];
  __shared__ __attribute__((aligned(16))) u16 Vp_s[64 * LVP];
  __shared__ __attribute__((aligned(16))) u16 P_s[128 * LP];

  int n0 = blockIdx.x * 128;
  int bh = blockIdx.y;
  int b = bh >> 3, h = bh & 7;
  long qbase = ((long)b * N_ + n0) * 512 + h * 64;
  const u16* Kpb = Kp + ((long)b * KD_) * 512 + h * 64;
  const u16* Vpb = Vpt + ((long)b * 512 + h * 64) * KD_;

  int tid = threadIdx.x;
#pragma unroll
  for (int i = 0; i < 2; ++i) {
    int c = tid + i * 512;
    int r = c >> 3, c8 = (c & 7) * 8;
    *reinterpret_cast<uint4*>(&Q_s[r * LQ + c8]) =
        *reinterpret_cast<const uint4*>(Q + qbase + (long)r * 512 + c8);
  }
#pragma unroll
  for (int i = 0; i < 4; ++i) {
    int c = tid + i * 512;
    int r = c >> 3, c8 = (c & 7) * 8;
    *reinterpret_cast<uint4*>(&Kp_s[r * LKP + c8]) =
        *reinterpret_cast<const uint4*>(Kpb + (long)r * 512 + c8);
  }
#pragma unroll
  for (int i = 0; i < 4; ++i) {
    int c = tid + i * 512;
    int r = c >> 5, c8 = (c & 31) * 8;
    *reinterpret_cast<uint4*>(&Vp_s[r * LVP + c8]) =
        *reinterpret_cast<const uint4*>(Vpb + (long)r * KD_ + c8);
  }
  __syncthreads();

  int lane = tid & 63, w = tid >> 6;
  int q0 = w * 16;
  int lr = lane & 15, lk = (lane >> 4) * 8;
  int lc = lane & 15, rb = (lane >> 4) * 4;

  f32x4 acc[16] = {};
  short8 af0 = *reinterpret_cast<const short8*>(&Q_s[(q0 + lr) * LQ + lk]);
  short8 af1 = *reinterpret_cast<const short8*>(&Q_s[(q0 + lr) * LQ + 32 + lk]);
#pragma unroll
  for (int t = 0; t < 16; ++t) {
    short8 b0 = *reinterpret_cast<const short8*>(&Kp_s[(t * 16 + lr) * LKP + lk]);
    short8 b1 = *reinterpret_cast<const short8*>(&Kp_s[(t * 16 + lr) * LKP + 32 + lk]);
    acc[t] = MFMA16(af0, b0, acc[t], 0, 0, 0);
    acc[t] = MFMA16(af1, b1, acc[t], 0, 0, 0);
  }

  float mx[4] = {-3.4e38f, -3.4e38f, -3.4e38f, -3.4e38f};
#pragma unroll
  for (int t = 0; t < 16; ++t)
#pragma unroll
    for (int r = 0; r < 4; ++r) {
      acc[t][r] *= 0.125f;
      mx[r] = fmaxf(mx[r], acc[t][r]);
    }
#pragma unroll
  for (int o = 1; o < 16; o <<= 1)
#pragma unroll
    for (int r = 0; r < 4; ++r) mx[r] = fmaxf(mx[r], __shfl_xor(mx[r], o));
  float sm[4] = {0.f, 0.f, 0.f, 0.f};
#pragma unroll
  for (int t = 0; t < 16; ++t)
#pragma unroll
    for (int r = 0; r < 4; ++r) {
      float e = __expf(acc[t][r] - mx[r]);
      acc[t][r] = e;
      sm[r] += e;
    }
#pragma unroll
  for (int o = 1; o < 16; o <<= 1)
#pragma unroll
    for (int r = 0; r < 4; ++r) sm[r] += __shfl_xor(sm[r], o);
  float inv[4];
#pragma unroll
  for (int r = 0; r < 4; ++r) inv[r] = 1.f / sm[r];
#pragma unroll
  for (int t = 0; t < 16; ++t)
#pragma unroll
    for (int r = 0; r < 4; ++r)
      P_s[(q0 + rb + r) * LP + t * 16 + lc] = f2bf(acc[t][r] * inv[r]);

  f32x4 o2[4] = {};
#pragma unroll
  for (int kk = 0; kk < 8; ++kk) {
    short8 pa = *reinterpret_cast<const short8*>(&P_s[(q0 + lr) * LP + kk * 32 + lk]);
#pragma unroll
    for (int nj = 0; nj < 4; ++nj) {
      short8 vb = *reinterpret_cast<const short8*>(&Vp_s[(nj * 16 + lr) * LVP + kk * 32 + lk]);
      o2[nj] = MFMA16(pa, vb, o2[nj], 0, 0, 0);
    }
  }
#pragma unroll
  for (int nj = 0; nj < 4; ++nj)
#pragma unroll
    for (int r = 0; r < 4; ++r)
      O[qbase + (long)(q0 + rb + r) * 512 + nj * 16 + lc] = f2bf(o2[nj][r]);
}

// ---------------- residual add + LayerNorm (row of 512) ----------------
__global__ __launch_bounds__(256) void add_ln_kernel(
    const float* __restrict__ xin32, const u16* __restrict__ xinb,
    const u16* __restrict__ yin, const u16* __restrict__ yin2,
    const float* __restrict__ bias2, const float* __restrict__ g,
    const float* __restrict__ bt, float* __restrict__ xout32,
    u16* __restrict__ xbout) {
  int row = blockIdx.x * 4 + (threadIdx.x >> 6);
  int lane = threadIdx.x & 63;
  int c0 = lane * 8;
  long base = (long)row * C_ + c0;
  float s[8];
  if (xin32) {
    float4 a0 = *reinterpret_cast<const float4*>(xin32 + base);
    float4 a1 = *reinterpret_cast<const float4*>(xin32 + base + 4);
    s[0] = a0.x; s[1] = a0.y; s[2] = a0.z; s[3] = a0.w;
    s[4] = a1.x; s[5] = a1.y; s[6] = a1.z; s[7] = a1.w;
  } else {
    ushort4 x0 = *reinterpret_cast<const ushort4*>(xinb + base);
    ushort4 x1 = *reinterpret_cast<const ushort4*>(xinb + base + 4);
    s[0] = bf2f(x0.x); s[1] = bf2f(x0.y); s[2] = bf2f(x0.z); s[3] = bf2f(x0.w);
    s[4] = bf2f(x1.x); s[5] = bf2f(x1.y); s[6] = bf2f(x1.z); s[7] = bf2f(x1.w);
  }
  ushort4 u0 = *reinterpret_cast<const ushort4*>(yin + base);
  ushort4 u1 = *reinterpret_cast<const ushort4*>(yin + base + 4);
  s[0] += bf2f(u0.x); s[1] += bf2f(u0.y); s[2] += bf2f(u0.z); s[3] += bf2f(u0.w);
  s[4] += bf2f(u1.x); s[5] += bf2f(u1.y); s[6] += bf2f(u1.z); s[7] += bf2f(u1.w);
  if (yin2) {
    ushort4 v0 = *reinterpret_cast<const ushort4*>(yin2 + base);
    ushort4 v1 = *reinterpret_cast<const ushort4*>(yin2 + base + 4);
    s[0] += bf2f(v0.x); s[1] += bf2f(v0.y); s[2] += bf2f(v0.z); s[3] += bf2f(v0.w);
    s[4] += bf2f(v1.x); s[5] += bf2f(v1.y); s[6] += bf2f(v1.z); s[7] += bf2f(v1.w);
  }
  if (bias2) {
#pragma unroll
    for (int i = 0; i < 8; ++i) s[i] += bias2[c0 + i];
  }
  float sum = 0.f;
#pragma unroll
  for (int i = 0; i < 8; ++i) sum += s[i];
#pragma unroll
  for (int o = 1; o < 64; o <<= 1) sum += __shfl_xor(sum, o);
  float mean = sum * (1.f / C_);
  float var = 0.f;
#pragma unroll
  for (int i = 0; i < 8; ++i) { float d = s[i] - mean; var += d * d; }
#pragma unroll
  for (int o = 1; o < 64; o <<= 1) var += __shfl_xor(var, o);
  float inv = rsqrtf(var * (1.f / C_) + 1e-5f);
  float o[8];
#pragma unroll
  for (int i = 0; i < 8; ++i) o[i] = (s[i] - mean) * inv * g[c0 + i] + bt[c0 + i];
  if (xout32) {
    float4 f0 = {o[0], o[1], o[2], o[3]};
    float4 f1 = {o[4], o[5], o[6], o[7]};
    *reinterpret_cast<float4*>(xout32 + base) = f0;
    *reinterpret_cast<float4*>(xout32 + base + 4) = f1;
  }
  if (xbout) {
    ushort4 w0 = {f2bf(o[0]), f2bf(o[1]), f2bf(o[2]), f2bf(o[3])};
    ushort4 w1 = {f2bf(o[4]), f2bf(o[5]), f2bf(o[6]), f2bf(o[7])};
    *reinterpret_cast<ushort4*>(xbout + base) = w0;
    *reinterpret_cast<ushort4*>(xbout + base + 4) = w1;
  }
}

extern "C" void kernel_launch(void* const* d_in, const int* in_sizes, int n_in,
                              void* d_out, int out_size, void* d_ws, size_t ws_size,
                              hipStream_t stream) {
  const float* x    = (const float*)d_in[0];
  const float* Wq   = (const float*)d_in[1];
  const float* Wk   = (const float*)d_in[2];
  const float* Wv   = (const float*)d_in[3];
  const float* Wo   = (const float*)d_in[4];
  const float* bo   = (const float*)d_in[5];
  const float* ln1g = (const float*)d_in[6];
  const float* ln1b = (const float*)d_in[7];
  const float* W1   = (const float*)d_in[8];
  const float* b1   = (const float*)d_in[9];
  const float* W2   = (const float*)d_in[10];
  const float* b2   = (const float*)d_in[11];
  const float* ln2g = (const float*)d_in[12];
  const float* ln2b = (const float*)d_in[13];
  const float* Ew   = (const float*)d_in[14];
  const float* Eb   = (const float*)d_in[15];
  float* xc = (float*)d_out;  // final f32 output only

  char* wsp = (char*)d_ws;
  size_t off = 0;
  auto alloc = [&](size_t bytes) -> void* {
    void* p = wsp + off;
    off = (off + bytes + 255) & ~(size_t)255;
    return p;
  };
  u16* xb  = (u16*)alloc(8388608UL * 2);    // x bf16 [B,N,C]
  u16* BIG = (u16*)alloc(33554432UL * 2);   // 64MB: xT+xE-partials | h1 [16384,2048]
  u16* Qb  = (u16*)alloc(8388608UL * 2);    // Q; attn-out in place
  u16* yb  = (u16*)alloc(8388608UL * 2);    // y bf16 (attn path)
  u16* Pp  = (u16*)alloc(16777216UL * 2);   // W2 partials p0,p1 [16384,512] each
  u16* xEb = (u16*)alloc(524288UL * 2);
  u16* Kpb = (u16*)alloc(524288UL * 2);
  u16* Vpt = (u16*)alloc(524288UL * 2);
  u16* wqb = (u16*)alloc(524288UL * 2);
  u16* wkb = (u16*)alloc(524288UL * 2);
  u16* wvb = (u16*)alloc(524288UL * 2);
  u16* wob = (u16*)alloc(524288UL * 2);
  u16* w1b = (u16*)alloc(2097152UL * 2);
  u16* w2b = (u16*)alloc(2097152UL * 2);
  u16* ewb = (u16*)alloc(1048576UL * 2);
  (void)ws_size; (void)in_sizes; (void)n_in; (void)out_size;

  cvt_kernel<<<dim3(8192), dim3(256), 0, stream>>>(x, xb, 2097152);
  Segs sg;
  sg.src[0] = Wq; sg.dst[0] = wqb;
  sg.src[1] = Wk; sg.dst[1] = wkb;
  sg.src[2] = Wv; sg.dst[2] = wvb;
  sg.src[3] = Wo; sg.dst[3] = wob;
  sg.src[4] = W1; sg.dst[4] = w1b;
  sg.src[5] = W2; sg.dst[5] = w2b;
  sg.src[6] = Ew; sg.dst[6] = ewb;
  sg.endblk[0] = 512;  sg.endblk[1] = 1024; sg.endblk[2] = 1536;
  sg.endblk[3] = 2048; sg.endblk[4] = 4096; sg.endblk[5] = 6144;
  sg.endblk[6] = 7168;
  cvt_multi_kernel<<<dim3(7168), dim3(256), 0, stream>>>(sg);

  for (int l = 0; l < L_; ++l) {
    const u16* wq = wqb + (long)l * 262144;
    const u16* wk = wkb + (long)l * 262144;
    const u16* wv = wvb + (long)l * 262144;
    const u16* wo = wob + (long)l * 262144;
    const u16* w1 = w1b + (long)l * 1048576;
    const u16* w2 = w2b + (long)l * 1048576;

    // ---- phase A: shared E-projection ----
    u16* xT = BIG;
    float* partF = (float*)(BIG + 8388608);
    transpose_kernel<<<dim3(64, 8, 4), dim3(256), 0, stream>>>(xb, xT);
    gemm_nt<128, 128, 7, 8><<<dim3(2, 4, 32), dim3(256), 0, stream>>>(
        ewb, xT, partF, nullptr, 4096, 4096, 4096, 512,
        0, 2097152, 131072, 524288, 4, 1.f, nullptr, nullptr);
    reduce8_kernel<<<dim3(512), dim3(256), 0, stream>>>(partF, xEb);
    gemm_nt<128, 128, 10, 1><<<dim3(2, 4, 8), dim3(256), 0, stream>>>(
        xEb, wk, Kpb, Eb, 512, 512, 512, 512,
        0, 0, 0, 0, 8, 1.f, wv, Vpt);
    // Q = x @ Wq^T  (128^2, 4 waves, 2 blocks/CU)
    gemm8p<128, 128, 64, 64, 4, 0><<<dim3(128, 4), dim3(256), 0, stream>>>(
        xb, wq, Qb, nullptr, 512, 512, 512, 512, 0, 0, 0);

    // ---- phase B: fused attention ----
    attn_kernel<<<dim3(32, 32), dim3(512), 0, stream>>>(Qb, Kpb, Vpt, Qb);

    // y = o @ Wo^T + bo
    gemm8p<128, 128, 64, 64, 4, 1><<<dim3(128, 4), dim3(256), 0, stream>>>(
        Qb, wo, yb, bo + (long)l * 512, 512, 512, 512, 512, 0, 0, 0);
    add_ln_kernel<<<dim3(4096), dim3(256), 0, stream>>>(
        l == 0 ? x : nullptr, l == 0 ? nullptr : xb, yb, nullptr, nullptr,
        ln1g + (long)l * 512, ln1b + (long)l * 512, nullptr, xb);

    // ---- phase C: FFN ----
    u16* h1 = BIG;  // [16384, 2048]
    gemm8p<128, 128, 64, 64, 4, 2><<<dim3(128, 16), dim3(256), 0, stream>>>(
        xb, w1, h1, b1 + (long)l * 2048, 512, 512, 512, 2048, 0, 0, 0);
    gemm8p<128, 128, 64, 64, 4, 0><<<dim3(128, 4, 2), dim3(256), 0, stream>>>(
        h1, w2, Pp, nullptr, 1024, 2048, 2048, 512, 1024, 1024, 8388608);
    add_ln_kernel<<<dim3(4096), dim3(256), 0, stream>>>(
        nullptr, xb, Pp, Pp + 8388608, b2 + (long)l * 512,
        ln2g + (long)l * 512, ln2b + (long)l * 512,
        (l == L_ - 1) ? xc : nullptr, (l == L_ - 1) ? (u16*)nullptr : xb);
  }
}

// Round 15
// 554.911 us; speedup vs baseline: 1.0536x; 1.0536x over previous
//
#include <hip/hip_runtime.h>
#include <math.h>

typedef unsigned short u16;
typedef __attribute__((ext_vector_type(8))) short short8;
typedef __attribute__((ext_vector_type(4))) float f32x4;

#define B_ 4
#define N_ 4096
#define C_ 512
#define H_ 8
#define D_ 64
#define KD_ 256
#define FF_ 2048
#define L_ 2

__device__ __forceinline__ float bf2f(u16 x) {
  return __builtin_bit_cast(float, (unsigned int)x << 16);
}
__device__ __forceinline__ u16 f2bf(float f) {
  unsigned int t = __builtin_bit_cast(unsigned int, f);
  return (u16)((t + 0x7fffu + ((t >> 16) & 1u)) >> 16);
}
// sigmoid-form tanh-GELU: 0.5(1+tanh(u)) == sigmoid(2u); ~8 VALU, no divide
__device__ __forceinline__ float fast_gelu(float t) {
  float z = t * (1.5957691216f + 0.0713548163f * t * t);
  float e = __expf(-z);
  return t * __builtin_amdgcn_rcpf(1.f + e);
}

#define GLD(g, l)                                                             \
  __builtin_amdgcn_global_load_lds(                                           \
      (const __attribute__((address_space(1))) void*)(g),                     \
      (__attribute__((address_space(3))) void*)(l), 16, 0, 0)

#define MFMA16 __builtin_amdgcn_mfma_f32_16x16x32_bf16

// ---------------- fused multi-tensor f32 -> bf16 (x + all weights) ----------------
struct Segs {
  const float* src[8];
  u16* dst[8];
  int endblk[8];
};
__global__ __launch_bounds__(256) void cvt_multi_kernel(Segs sg) {
  int b = blockIdx.x;
  int i = 0;
#pragma unroll
  for (int k = 0; k < 7; ++k) i += (b >= sg.endblk[k]);
  int start = (i == 0) ? 0 : sg.endblk[i - 1];
  int idx = (b - start) * 256 + threadIdx.x;
  float4 v = reinterpret_cast<const float4*>(sg.src[i])[idx];
  ushort4 o;
  o.x = f2bf(v.x); o.y = f2bf(v.y); o.z = f2bf(v.z); o.w = f2bf(v.w);
  reinterpret_cast<ushort4*>(sg.dst[i])[idx] = o;
}

// ---------------- bf16 transpose [B,N,C] -> [B,C,N], 64x64 tiles ----------------
__global__ __launch_bounds__(256) void transpose_kernel(const u16* __restrict__ in,
                                                        u16* __restrict__ out) {
  __shared__ u16 T[64][72];
  int n0 = blockIdx.x * 64, c0 = blockIdx.y * 64, b = blockIdx.z;
  const u16* src = in + (long)b * N_ * C_;
  u16* dst = out + (long)b * C_ * N_;
  int t = threadIdx.x;
  int r = t >> 3, cq = (t & 7) * 8;
#pragma unroll
  for (int h = 0; h < 2; ++h) {
    const u16* p = src + (long)(n0 + r + h * 32) * C_ + c0 + cq;
    ushort4 v0 = *reinterpret_cast<const ushort4*>(p);
    ushort4 v1 = *reinterpret_cast<const ushort4*>(p + 4);
    T[r + h * 32][cq + 0] = v0.x; T[r + h * 32][cq + 1] = v0.y;
    T[r + h * 32][cq + 2] = v0.z; T[r + h * 32][cq + 3] = v0.w;
    T[r + h * 32][cq + 4] = v1.x; T[r + h * 32][cq + 5] = v1.y;
    T[r + h * 32][cq + 6] = v1.z; T[r + h * 32][cq + 7] = v1.w;
  }
  __syncthreads();
  int cc = t >> 3, nq = (t & 7) * 8;
#pragma unroll
  for (int h = 0; h < 2; ++h) {
    int cl = cc + h * 32;
    ushort4 w0, w1;
    w0.x = T[nq + 0][cl]; w0.y = T[nq + 1][cl];
    w0.z = T[nq + 2][cl]; w0.w = T[nq + 3][cl];
    w1.x = T[nq + 4][cl]; w1.y = T[nq + 5][cl];
    w1.z = T[nq + 6][cl]; w1.w = T[nq + 7][cl];
    u16* q = dst + (long)(c0 + cl) * N_ + n0 + nq;
    *reinterpret_cast<ushort4*>(q) = w0;
    *reinterpret_cast<ushort4*>(q + 4) = w1;
  }
}

// ---------------- counted-vmcnt single-barrier MFMA GEMM (NT) ----------------
// C[m,j] = sum_k A[m,k]*B[j,k]. BK=32, 4 LDS buffers (3-deep prefetch), ONE
// barrier per K-tile. Counted vmcnt never drains to 0 in the loop. ds_read ->
// MFMA waits left to the compiler (fine-grained lgkmcnt, no blanket drain).
// MFMA operands swapped (bf first): lane holds 4 consecutive j for row lane&15.
// Epilogue stages C tile through LDS scratch (wave-private, in As[0..1]) so
// global stores are 16B/lane contiguous. Last tile only reads buffer 3.
// Wave coverage invariant: 8 waves * WM * WN == BM * BN (static_assert).
// EPI: 0 bf16 | 1 bf16 +bias[j] | 2 bf16 gelu(v+bias[j])
template <int BM, int BN, int WM, int WN, int EPI>
__global__ __launch_bounds__(512, 2) void gemm8p(
    const u16* __restrict__ A, const u16* __restrict__ B, u16* __restrict__ C,
    const float* __restrict__ bias, int K, int lda, int ldb, int ldc,
    long sAz, long sBz, long sCz) {
  constexpr int BK = 32;
  constexpr int GA = BM / 128, GB = BN / 128, G = GA + GB;
  constexpr int FM = WM / 16, FN = WN / 16;
  constexpr int NWN = BN / WN;
  static_assert(8 * WM * WN == BM * BN, "8-wave tile coverage mismatch");
  static_assert((8 / NWN) * WM == BM, "M-wave coverage mismatch");
  static_assert(WN == 64, "epilogue assumes WN==64");
  constexpr int ASZ = BM * BK, BSZ = BN * BK;
  constexpr int EPAD = 72;  // scratch row stride (u16): 64 cols + 8 pad

  __shared__ __attribute__((aligned(16))) u16 As[4][ASZ];
  __shared__ __attribute__((aligned(16))) u16 Bs[4][BSZ];

  A += (long)blockIdx.z * sAz;
  B += (long)blockIdx.z * sBz;
  C += (long)blockIdx.z * sCz;

  int gy = gridDim.y;
  int nwg = gridDim.x * gy;
  int id = blockIdx.x * gy + blockIdx.y;
  int nid = (id & 7) * (nwg >> 3) + (id >> 3);
  int row0 = (nid / gy) * BM, col0 = (nid % gy) * BN;

  int tid = threadIdx.x;
  int lane = tid & 63, wid = tid >> 6;
  int wr = wid / NWN, wc = wid % NWN;
  int lr = lane & 15, q = lane >> 4;

  // hoisted per-thread global stage sources (stage addr = gX[g] + k0)
  const u16* gA[GA];
  const u16* gB[GB];
#pragma unroll
  for (int g = 0; g < GA; ++g) {
    int c = g * 512 + tid, r = c >> 2, ck = c & 3;
    gA[g] = A + (long)(row0 + r) * lda + ((ck ^ ((r >> 1) & 3)) << 3);
  }
#pragma unroll
  for (int g = 0; g < GB; ++g) {
    int c = g * 512 + tid, r = c >> 2, ck = c & 3;
    gB[g] = B + (long)(col0 + r) * ldb + ((ck ^ ((r >> 1) & 3)) << 3);
  }

  auto stA = [&](int buf, int k0) {
#pragma unroll
    for (int g = 0; g < GA; ++g)
      GLD(gA[g] + k0, &As[buf][(g * 512 + tid) * 8]);
  };
  auto stB = [&](int buf, int k0) {
#pragma unroll
    for (int g = 0; g < GB; ++g)
      GLD(gB[g] + k0, &Bs[buf][(g * 512 + tid) * 8]);
  };
  auto rdA = [&](int buf, int r) {
    return *reinterpret_cast<const short8*>(
        &As[buf][r * 32 + ((q ^ ((r >> 1) & 3)) << 3)]);
  };
  auto rdB = [&](int buf, int r) {
    return *reinterpret_cast<const short8*>(
        &Bs[buf][r * 32 + ((q ^ ((r >> 1) & 3)) << 3)]);
  };

  f32x4 acc[FM][FN] = {};
  int NT = K / BK;  // always a multiple of 4

  stA(0, 0); stB(0, 0);
  stA(1, BK); stB(1, BK);
  stA(2, 2 * BK); stB(2, 2 * BK);

  for (int tt = 0; tt < NT; tt += 4) {
#pragma unroll
    for (int u = 0; u < 4; ++u) {  // buffer index = u (compile-time)
      int t = tt + u;
      bool pf = (t + 3) < NT;
      int kn = (t + 3) * BK;

      // tile t landed (mine via counted vmcnt; everyone's via barrier);
      // tiles t+1, t+2 (2G loads) stay in flight across the barrier
      if constexpr (G == 4) asm volatile("s_waitcnt vmcnt(8)" ::: "memory");
      else                  asm volatile("s_waitcnt vmcnt(6)" ::: "memory");
      __builtin_amdgcn_s_barrier();

      short8 bf[FN], af[FM];
#pragma unroll
      for (int nj = 0; nj < FN; ++nj) bf[nj] = rdB(u, wc * WN + nj * 16 + lr);
#pragma unroll
      for (int mi = 0; mi < FM; ++mi) af[mi] = rdA(u, wr * WM + mi * 16 + lr);
      if (pf) { stA((u + 3) & 3, kn); stB((u + 3) & 3, kn); }
      // compiler inserts fine-grained lgkmcnt before each dependent MFMA;
      // all tile-t ds_read uses complete before the next barrier, so the
      // stage into buf[(t-1)&3] at tile t+1 remains race-free.
      __builtin_amdgcn_s_setprio(1);
#pragma unroll
      for (int mi = 0; mi < FM; ++mi)
#pragma unroll
        for (int nj = 0; nj < FN; ++nj)
          acc[mi][nj] = MFMA16(bf[nj], af[mi], acc[mi][nj], 0, 0, 0);
      __builtin_amdgcn_s_setprio(0);
    }
  }

  // ---- epilogue: LDS-staged coalesced stores ----
  u16* esc = &As[0][0] + wid * (16 * EPAD);  // 2304B/wave, 18KB total
  int lm = lane & 15, jb4 = (lane >> 4) * 4;
  int erow = lane >> 3, ecol = (lane & 7) * 8;
  float4 bv[FN];
  if constexpr (EPI == 1 || EPI == 2) {
#pragma unroll
    for (int nj = 0; nj < FN; ++nj)
      bv[nj] = *reinterpret_cast<const float4*>(&bias[col0 + wc * WN + nj * 16 + jb4]);
  }
#pragma unroll
  for (int mi = 0; mi < FM; ++mi) {
    long mbase = row0 + wr * WM + mi * 16;
#pragma unroll
    for (int nj = 0; nj < FN; ++nj) {
      f32x4 v = acc[mi][nj];
      ushort4 o;
      if constexpr (EPI == 0) {
        o.x = f2bf(v[0]); o.y = f2bf(v[1]); o.z = f2bf(v[2]); o.w = f2bf(v[3]);
      } else if constexpr (EPI == 1) {
        o.x = f2bf(v[0] + bv[nj].x); o.y = f2bf(v[1] + bv[nj].y);
        o.z = f2bf(v[2] + bv[nj].z); o.w = f2bf(v[3] + bv[nj].w);
      } else {
        o.x = f2bf(fast_gelu(v[0] + bv[nj].x)); o.y = f2bf(fast_gelu(v[1] + bv[nj].y));
        o.z = f2bf(fast_gelu(v[2] + bv[nj].z)); o.w = f2bf(fast_gelu(v[3] + bv[nj].w));
      }
      *reinterpret_cast<ushort4*>(&esc[lm * EPAD + nj * 16 + jb4]) = o;
    }
    asm volatile("s_waitcnt lgkmcnt(0)" ::: "memory");
#pragma unroll
    for (int p = 0; p < 2; ++p) {
      int r = p * 8 + erow;
      uint4 w = *reinterpret_cast<const uint4*>(&esc[r * EPAD + ecol]);
      *reinterpret_cast<uint4*>(&C[(mbase + r) * ldc + col0 + wc * WN + ecol]) = w;
    }
    asm volatile("s_waitcnt lgkmcnt(0)" ::: "memory");  // reads done before next writes
  }
}

// ---------------- generic 128-tile NT MFMA GEMM (phase A) ----------------
// EPI: 7 f32 split-K partial | 10 fused Kp/Vp (z<4: Kp; z>=4: Vp via B2/Cout2)
template <int BM, int BN, int EPI, int SPLITK>
__global__ __launch_bounds__(256, 2) void gemm_nt(
    const u16* __restrict__ A, const u16* B, void* __restrict__ Cout,
    const float* __restrict__ bias, int K, int lda, int ldb, int ldc,
    long sA1, long sB1, long sC1, long sCh, int nz, float alpha,
    const u16* __restrict__ B2, void* __restrict__ Cout2) {
  constexpr int BK = 64;
  constexpr int WM = BM / 2, WN = BN / 2;
  constexpr int FM = WM / 16, FN = WN / 16;
  constexpr int CA = BM / 32, CB = BN / 32;

  __shared__ __attribute__((aligned(16))) u16 As[BM * BK];
  __shared__ __attribute__((aligned(16))) u16 Bs[BN * BK];

  int z, chunk, kv = 0;
  long coff;
  if constexpr (EPI == 10) {
    z = blockIdx.z; chunk = 0;
    kv = z >> 2;
    int zbq = z & 3;
    A += (long)zbq * 131072;
    if (kv) B = B2;
    coff = (long)zbq * 131072;
  } else {
    if constexpr (SPLITK > 1) { z = blockIdx.z % nz; chunk = blockIdx.z / nz; }
    else { z = blockIdx.z; chunk = 0; }
    A += (long)z * sA1;
    B += (long)z * sB1;
    coff = (long)z * sC1 + (long)chunk * sCh;
  }

  int tid = threadIdx.x;
  int lane = tid & 63, wid = tid >> 6;
  int wr = wid >> 1, wc = wid & 1;
  int row0 = blockIdx.x * BM, col0 = blockIdx.y * BN;

  int Kc = K / SPLITK;
  int kbeg = chunk * Kc;

  f32x4 acc[FM][FN] = {};

  for (int k0 = kbeg; k0 < kbeg + Kc; k0 += BK) {
#pragma unroll
    for (int i = 0; i < CA; ++i) {
      int c = tid + i * 256;
      GLD(A + (long)(row0 + (c >> 3)) * lda + k0 + (c & 7) * 8, As + c * 8);
    }
#pragma unroll
    for (int i = 0; i < CB; ++i) {
      int c = tid + i * 256;
      GLD(B + (long)(col0 + (c >> 3)) * ldb + k0 + (c & 7) * 8, Bs + c * 8);
    }
    __syncthreads();

    int lr = lane & 15, lk = (lane >> 4) * 8;
#pragma unroll
    for (int kk = 0; kk < BK; kk += 32) {
      short8 af[FM], bfr[FN];
#pragma unroll
      for (int mi = 0; mi < FM; ++mi)
        af[mi] = *reinterpret_cast<const short8*>(&As[(wr * WM + mi * 16 + lr) * BK + kk + lk]);
#pragma unroll
      for (int nj = 0; nj < FN; ++nj)
        bfr[nj] = *reinterpret_cast<const short8*>(&Bs[(wc * WN + nj * 16 + lr) * BK + kk + lk]);
#pragma unroll
      for (int mi = 0; mi < FM; ++mi)
#pragma unroll
        for (int nj = 0; nj < FN; ++nj)
          acc[mi][nj] = MFMA16(af[mi], bfr[nj], acc[mi][nj], 0, 0, 0);
    }
    __syncthreads();
  }

  int lc = lane & 15, rb = (lane >> 4) * 4;
#pragma unroll
  for (int mi = 0; mi < FM; ++mi) {
#pragma unroll
    for (int nj = 0; nj < FN; ++nj) {
      int j = col0 + wc * WN + nj * 16 + lc;
      int m0 = row0 + wr * WM + mi * 16 + rb;
#pragma unroll
      for (int r = 0; r < 4; ++r) {
        int m = m0 + r;
        float v = acc[mi][nj][r];
        if constexpr (EPI == 10) {
          if (kv == 0)
            reinterpret_cast<u16*>(Cout)[coff + (long)m * 512 + j] = f2bf(v + bias[m]);
          else
            reinterpret_cast<u16*>(Cout2)[coff + (long)j * 256 + m] = f2bf(v + bias[m]);
        } else {  // 7: f32 split-K partial
          reinterpret_cast<float*>(Cout)[coff + (long)m * ldc + j] = v;
        }
      }
    }
  }
}

// ---------------- split-K reduce: sum 8 f32 chunks -> bf16 ----------------
__global__ __launch_bounds__(256) void reduce8_kernel(const float* __restrict__ part,
                                                      u16* __restrict__ out) {
  int i = blockIdx.x * 256 + threadIdx.x;
  const float4* p = reinterpret_cast<const float4*>(part);
  float4 s = p[i];
#pragma unroll
  for (int c = 1; c < 8; ++c) {
    float4 t = p[i + c * 131072];
    s.x += t.x; s.y += t.y; s.z += t.z; s.w += t.w;
  }
  ushort4 o;
  o.x = f2bf(s.x); o.y = f2bf(s.y); o.z = f2bf(s.z); o.w = f2bf(s.w);
  reinterpret_cast<ushort4*>(out)[i] = o;
}

// ---------------- fused attention: S=Q.Kp^T, softmax, O=P.Vp ----------------
__global__ __launch_bounds__(512, 2) void attn_kernel(
    const u16* __restrict__ Q, const u16* __restrict__ Kp,
    const u16* __restrict__ Vpt, u16* __restrict__ O) {
  constexpr int LQ = 72, LKP = 72, LVP = 264, LP = 264;
  __shared__ __attribute__((aligned(16))) u16 Q_s[128 * LQ];
  __shared__ __attribute__((aligned(16))) u16 Kp_s[256 * LKP];
  __shared__ __attribute__((aligned(16))) u16 Vp_s[64 * LVP];
  __shared__ __attribute__((aligned(16))) u16 P_s[128 * LP];

  int n0 = blockIdx.x * 128;
  int bh = blockIdx.y;
  int b = bh >> 3, h = bh & 7;
  long qbase = ((long)b * N_ + n0) * 512 + h * 64;
  const u16* Kpb = Kp + ((long)b * KD_) * 512 + h * 64;
  const u16* Vpb = Vpt + ((long)b * 512 + h * 64) * KD_;

  int tid = threadIdx.x;
#pragma unroll
  for (int i = 0; i < 2; ++i) {
    int c = tid + i * 512;
    int r = c >> 3, c8 = (c & 7) * 8;
    *reinterpret_cast<uint4*>(&Q_s[r * LQ + c8]) =
        *reinterpret_cast<const uint4*>(Q + qbase + (long)r * 512 + c8);
  }
#pragma unroll
  for (int i = 0; i < 4; ++i) {
    int c = tid + i * 512;
    int r = c >> 3, c8 = (c & 7) * 8;
    *reinterpret_cast<uint4*>(&Kp_s[r * LKP + c8]) =
        *reinterpret_cast<const uint4*>(Kpb + (long)r * 512 + c8);
  }
#pragma unroll
  for (int i = 0; i < 4; ++i) {
    int c = tid + i * 512;
    int r = c >> 5, c8 = (c & 31) * 8;
    *reinterpret_cast<uint4*>(&Vp_s[r * LVP + c8]) =
        *reinterpret_cast<const uint4*>(Vpb + (long)r * KD_ + c8);
  }
  __syncthreads();

  int lane = tid & 63, w = tid >> 6;
  int q0 = w * 16;
  int lr = lane & 15, lk = (lane >> 4) * 8;
  int lc = lane & 15, rb = (lane >> 4) * 4;

  f32x4 acc[16] = {};
  short8 af0 = *reinterpret_cast<const short8*>(&Q_s[(q0 + lr) * LQ + lk]);
  short8 af1 = *reinterpret_cast<const short8*>(&Q_s[(q0 + lr) * LQ + 32 + lk]);
#pragma unroll
  for (int t = 0; t < 16; ++t) {
    short8 b0 = *reinterpret_cast<const short8*>(&Kp_s[(t * 16 + lr) * LKP + lk]);
    short8 b1 = *reinterpret_cast<const short8*>(&Kp_s[(t * 16 + lr) * LKP + 32 + lk]);
    acc[t] = MFMA16(af0, b0, acc[t], 0, 0, 0);
    acc[t] = MFMA16(af1, b1, acc[t], 0, 0, 0);
  }

  float mx[4] = {-3.4e38f, -3.4e38f, -3.4e38f, -3.4e38f};
#pragma unroll
  for (int t = 0; t < 16; ++t)
#pragma unroll
    for (int r = 0; r < 4; ++r) {
      acc[t][r] *= 0.125f;
      mx[r] = fmaxf(mx[r], acc[t][r]);
    }
#pragma unroll
  for (int o = 1; o < 16; o <<= 1)
#pragma unroll
    for (int r = 0; r < 4; ++r) mx[r] = fmaxf(mx[r], __shfl_xor(mx[r], o));
  float sm[4] = {0.f, 0.f, 0.f, 0.f};
#pragma unroll
  for (int t = 0; t < 16; ++t)
#pragma unroll
    for (int r = 0; r < 4; ++r) {
      float e = __expf(acc[t][r] - mx[r]);
      acc[t][r] = e;
      sm[r] += e;
    }
#pragma unroll
  for (int o = 1; o < 16; o <<= 1)
#pragma unroll
    for (int r = 0; r < 4; ++r) sm[r] += __shfl_xor(sm[r], o);
  float inv[4];
#pragma unroll
  for (int r = 0; r < 4; ++r) inv[r] = 1.f / sm[r];
#pragma unroll
  for (int t = 0; t < 16; ++t)
#pragma unroll
    for (int r = 0; r < 4; ++r)
      P_s[(q0 + rb + r) * LP + t * 16 + lc] = f2bf(acc[t][r] * inv[r]);

  f32x4 o2[4] = {};
#pragma unroll
  for (int kk = 0; kk < 8; ++kk) {
    short8 pa = *reinterpret_cast<const short8*>(&P_s[(q0 + lr) * LP + kk * 32 + lk]);
#pragma unroll
    for (int nj = 0; nj < 4; ++nj) {
      short8 vb = *reinterpret_cast<const short8*>(&Vp_s[(nj * 16 + lr) * LVP + kk * 32 + lk]);
      o2[nj] = MFMA16(pa, vb, o2[nj], 0, 0, 0);
    }
  }
#pragma unroll
  for (int nj = 0; nj < 4; ++nj)
#pragma unroll
    for (int r = 0; r < 4; ++r)
      O[qbase + (long)(q0 + rb + r) * 512 + nj * 16 + lc] = f2bf(o2[nj][r]);
}

// ---------------- residual add + LayerNorm (row of 512) ----------------
__global__ __launch_bounds__(256) void add_ln_kernel(
    const float* __restrict__ xin32, const u16* __restrict__ xinb,
    const u16* __restrict__ yin, const u16* __restrict__ yin2,
    const float* __restrict__ bias2, const float* __restrict__ g,
    const float* __restrict__ bt, float* __restrict__ xout32,
    u16* __restrict__ xbout) {
  int row = blockIdx.x * 4 + (threadIdx.x >> 6);
  int lane = threadIdx.x & 63;
  int c0 = lane * 8;
  long base = (long)row * C_ + c0;
  float s[8];
  if (xin32) {
    float4 a0 = *reinterpret_cast<const float4*>(xin32 + base);
    float4 a1 = *reinterpret_cast<const float4*>(xin32 + base + 4);
    s[0] = a0.x; s[1] = a0.y; s[2] = a0.z; s[3] = a0.w;
    s[4] = a1.x; s[5] = a1.y; s[6] = a1.z; s[7] = a1.w;
  } else {
    ushort4 x0 = *reinterpret_cast<const ushort4*>(xinb + base);
    ushort4 x1 = *reinterpret_cast<const ushort4*>(xinb + base + 4);
    s[0] = bf2f(x0.x); s[1] = bf2f(x0.y); s[2] = bf2f(x0.z); s[3] = bf2f(x0.w);
    s[4] = bf2f(x1.x); s[5] = bf2f(x1.y); s[6] = bf2f(x1.z); s[7] = bf2f(x1.w);
  }
  ushort4 u0 = *reinterpret_cast<const ushort4*>(yin + base);
  ushort4 u1 = *reinterpret_cast<const ushort4*>(yin + base + 4);
  s[0] += bf2f(u0.x); s[1] += bf2f(u0.y); s[2] += bf2f(u0.z); s[3] += bf2f(u0.w);
  s[4] += bf2f(u1.x); s[5] += bf2f(u1.y); s[6] += bf2f(u1.z); s[7] += bf2f(u1.w);
  if (yin2) {
    ushort4 v0 = *reinterpret_cast<const ushort4*>(yin2 + base);
    ushort4 v1 = *reinterpret_cast<const ushort4*>(yin2 + base + 4);
    s[0] += bf2f(v0.x); s[1] += bf2f(v0.y); s[2] += bf2f(v0.z); s[3] += bf2f(v0.w);
    s[4] += bf2f(v1.x); s[5] += bf2f(v1.y); s[6] += bf2f(v1.z); s[7] += bf2f(v1.w);
  }
  if (bias2) {
#pragma unroll
    for (int i = 0; i < 8; ++i) s[i] += bias2[c0 + i];
  }
  float sum = 0.f;
#pragma unroll
  for (int i = 0; i < 8; ++i) sum += s[i];
#pragma unroll
  for (int o = 1; o < 64; o <<= 1) sum += __shfl_xor(sum, o);
  float mean = sum * (1.f / C_);
  float var = 0.f;
#pragma unroll
  for (int i = 0; i < 8; ++i) { float d = s[i] - mean; var += d * d; }
#pragma unroll
  for (int o = 1; o < 64; o <<= 1) var += __shfl_xor(var, o);
  float inv = rsqrtf(var * (1.f / C_) + 1e-5f);
  float o[8];
#pragma unroll
  for (int i = 0; i < 8; ++i) o[i] = (s[i] - mean) * inv * g[c0 + i] + bt[c0 + i];
  if (xout32) {
    float4 f0 = {o[0], o[1], o[2], o[3]};
    float4 f1 = {o[4], o[5], o[6], o[7]};
    *reinterpret_cast<float4*>(xout32 + base) = f0;
    *reinterpret_cast<float4*>(xout32 + base + 4) = f1;
  }
  if (xbout) {
    ushort4 w0 = {f2bf(o[0]), f2bf(o[1]), f2bf(o[2]), f2bf(o[3])};
    ushort4 w1 = {f2bf(o[4]), f2bf(o[5]), f2bf(o[6]), f2bf(o[7])};
    *reinterpret_cast<ushort4*>(xbout + base) = w0;
    *reinterpret_cast<ushort4*>(xbout + base + 4) = w1;
  }
}

extern "C" void kernel_launch(void* const* d_in, const int* in_sizes, int n_in,
                              void* d_out, int out_size, void* d_ws, size_t ws_size,
                              hipStream_t stream) {
  const float* x    = (const float*)d_in[0];
  const float* Wq   = (const float*)d_in[1];
  const float* Wk   = (const float*)d_in[2];
  const float* Wv   = (const float*)d_in[3];
  const float* Wo   = (const float*)d_in[4];
  const float* bo   = (const float*)d_in[5];
  const float* ln1g = (const float*)d_in[6];
  const float* ln1b = (const float*)d_in[7];
  const float* W1   = (const float*)d_in[8];
  const float* b1   = (const float*)d_in[9];
  const float* W2   = (const float*)d_in[10];
  const float* b2   = (const float*)d_in[11];
  const float* ln2g = (const float*)d_in[12];
  const float* ln2b = (const float*)d_in[13];
  const float* Ew   = (const float*)d_in[14];
  const float* Eb   = (const float*)d_in[15];
  float* xc = (float*)d_out;  // final f32 output only

  char* wsp = (char*)d_ws;
  size_t off = 0;
  auto alloc = [&](size_t bytes) -> void* {
    void* p = wsp + off;
    off = (off + bytes + 255) & ~(size_t)255;
    return p;
  };
  u16* xb  = (u16*)alloc(8388608UL * 2);    // x bf16 [B,N,C]
  u16* BIG = (u16*)alloc(33554432UL * 2);   // 64MB: xT+xE-partials | h1 [16384,2048]
  u16* Qb  = (u16*)alloc(8388608UL * 2);    // Q; attn-out in place
  u16* yb  = (u16*)alloc(8388608UL * 2);    // y bf16 (attn path)
  u16* Pp  = (u16*)alloc(16777216UL * 2);   // W2 partials p0,p1 [16384,512] each
  u16* xEb = (u16*)alloc(524288UL * 2);
  u16* Kpb = (u16*)alloc(524288UL * 2);
  u16* Vpt = (u16*)alloc(524288UL * 2);
  u16* wqb = (u16*)alloc(524288UL * 2);
  u16* wkb = (u16*)alloc(524288UL * 2);
  u16* wvb = (u16*)alloc(524288UL * 2);
  u16* wob = (u16*)alloc(524288UL * 2);
  u16* w1b = (u16*)alloc(2097152UL * 2);
  u16* w2b = (u16*)alloc(2097152UL * 2);
  u16* ewb = (u16*)alloc(1048576UL * 2);
  (void)ws_size; (void)in_sizes; (void)n_in; (void)out_size;

  // single fused convert launch: x + all weights
  Segs sg;
  sg.src[0] = x;  sg.dst[0] = xb;
  sg.src[1] = Wq; sg.dst[1] = wqb;
  sg.src[2] = Wk; sg.dst[2] = wkb;
  sg.src[3] = Wv; sg.dst[3] = wvb;
  sg.src[4] = Wo; sg.dst[4] = wob;
  sg.src[5] = W1; sg.dst[5] = w1b;
  sg.src[6] = W2; sg.dst[6] = w2b;
  sg.src[7] = Ew; sg.dst[7] = ewb;
  sg.endblk[0] = 8192;
  sg.endblk[1] = 8704;  sg.endblk[2] = 9216;  sg.endblk[3] = 9728;
  sg.endblk[4] = 10240; sg.endblk[5] = 12288; sg.endblk[6] = 14336;
  sg.endblk[7] = 15360;
  cvt_multi_kernel<<<dim3(15360), dim3(256), 0, stream>>>(sg);

  for (int l = 0; l < L_; ++l) {
    const u16* wq = wqb + (long)l * 262144;
    const u16* wk = wkb + (long)l * 262144;
    const u16* wv = wvb + (long)l * 262144;
    const u16* wo = wob + (long)l * 262144;
    const u16* w1 = w1b + (long)l * 1048576;
    const u16* w2 = w2b + (long)l * 1048576;

    // ---- phase A: shared E-projection ----
    u16* xT = BIG;
    float* partF = (float*)(BIG + 8388608);
    transpose_kernel<<<dim3(64, 8, 4), dim3(256), 0, stream>>>(xb, xT);
    gemm_nt<128, 128, 7, 8><<<dim3(2, 4, 32), dim3(256), 0, stream>>>(
        ewb, xT, partF, nullptr, 4096, 4096, 4096, 512,
        0, 2097152, 131072, 524288, 4, 1.f, nullptr, nullptr);
    reduce8_kernel<<<dim3(512), dim3(256), 0, stream>>>(partF, xEb);
    gemm_nt<128, 128, 10, 1><<<dim3(2, 4, 8), dim3(256), 0, stream>>>(
        xEb, wk, Kpb, Eb, 512, 512, 512, 512,
        0, 0, 0, 0, 8, 1.f, wv, Vpt);
    // Q = x @ Wq^T  (BM=256 BN=128, WM=64 WN=64 -> 4x2 waves)
    gemm8p<256, 128, 64, 64, 0><<<dim3(64, 4), dim3(512), 0, stream>>>(
        xb, wq, Qb, nullptr, 512, 512, 512, 512, 0, 0, 0);

    // ---- phase B: fused attention ----
    attn_kernel<<<dim3(32, 32), dim3(512), 0, stream>>>(Qb, Kpb, Vpt, Qb);

    // y = o @ Wo^T + bo
    gemm8p<256, 128, 64, 64, 1><<<dim3(64, 4), dim3(512), 0, stream>>>(
        Qb, wo, yb, bo + (long)l * 512, 512, 512, 512, 512, 0, 0, 0);
    add_ln_kernel<<<dim3(4096), dim3(256), 0, stream>>>(
        l == 0 ? x : nullptr, l == 0 ? nullptr : xb, yb, nullptr, nullptr,
        ln1g + (long)l * 512, ln1b + (long)l * 512, nullptr, xb);

    // ---- phase C: FFN ----
    u16* h1 = BIG;  // [16384, 2048]
    gemm8p<256, 256, 128, 64, 2><<<dim3(64, 8), dim3(512), 0, stream>>>(
        xb, w1, h1, b1 + (long)l * 2048, 512, 512, 512, 2048, 0, 0, 0);
    gemm8p<256, 256, 128, 64, 0><<<dim3(64, 2, 2), dim3(512), 0, stream>>>(
        h1, w2, Pp, nullptr, 1024, 2048, 2048, 512, 1024, 1024, 8388608);
    add_ln_kernel<<<dim3(4096), dim3(256), 0, stream>>>(
        nullptr, xb, Pp, Pp + 8388608, b2 + (long)l * 512,
        ln2g + (long)l * 512, ln2b + (long)l * 512,
        (l == L_ - 1) ? xc : nullptr, (l == L_ - 1) ? (u16*)nullptr : xb);
  }
}